// Round 7
// baseline (57.827 us; speedup 1.0000x reference)
//
#include <hip/hip_runtime.h>
#include <math.h>

// HyperConnections: out[(b*S+t), n, d] = sum_s M[t][s] * in[(b*S+s), n, d]
// M[t][s] = sinkhorn(H_res/tau)[s][t] + softmax(H_post)[t] * softmax(H_pre)[s]
//
// B=4, S=4, N=2048, D=1024, fp32. Memory-bound: 128 MiB in + 128 MiB out.
// Each thread owns one r in [0, N*D/4). ALL 16 input f4 (4 batches x 4
// streams) are loaded before the thread-0 Sinkhorn preamble and pinned live
// with empty asm (prevents the compiler from sinking the loads, which it did
// in the previous round: VGPR_Count was 32). HBM latency for the entire
// thread's read traffic overlaps the preamble + other waves; stores stream
// after the barrier.

#define HC_S 4
#define HC_TAU 0.05f
#define HC_ITERS 10

typedef float f4 __attribute__((ext_vector_type(4)));

// N*D/4 float4 elements per stream = 2048*1024/4 = 524288 = 2^19
constexpr int ND4 = (2048 * 1024) / 4;
constexpr size_t BATCH_STRIDE = (size_t)4 * ND4;   // 4 streams per batch

__device__ inline float lse4_fast(float a, float b, float c, float d) {
    float m = fmaxf(fmaxf(a, b), fmaxf(c, d));
    return m + __logf(__expf(a - m) + __expf(b - m) + __expf(c - m) + __expf(d - m));
}

#define KEEP_ALIVE(v) asm volatile("" : "+v"(v))

__global__ __launch_bounds__(256) void hc_mix_kernel(
    const f4* __restrict__ in, f4* __restrict__ out,
    const float* __restrict__ Hres, const float* __restrict__ Hpre,
    const float* __restrict__ Hpost)
{
    __shared__ float Ms[16];

    const size_t r = (size_t)blockIdx.x * 256 + threadIdx.x;   // 0 .. ND4-1

    // ---- issue ALL loads first: 16 x 16B per lane in flight ----
    f4 q[4][4];
    #pragma unroll
    for (int b = 0; b < 4; ++b) {
        const f4* pb = in + (size_t)b * BATCH_STRIDE + r;
        #pragma unroll
        for (int s = 0; s < 4; ++s)
            q[b][s] = pb[(size_t)s * ND4];
    }
    // Pin every loaded value live so the compiler cannot sink the loads
    // below the barrier / interleave them with stores.
    #pragma unroll
    for (int b = 0; b < 4; ++b)
        #pragma unroll
        for (int s = 0; s < 4; ++s)
            KEEP_ALIVE(q[b][s]);

    if (threadIdx.x == 0) {
        // --- log-domain Sinkhorn on 4x4 (10 iters, tau=0.05), fast-math ---
        float Z[HC_S][HC_S], u[HC_S], v[HC_S];
        #pragma unroll
        for (int i = 0; i < HC_S; ++i) { u[i] = 0.f; v[i] = 0.f; }
        #pragma unroll
        for (int i = 0; i < HC_S; ++i)
            #pragma unroll
            for (int j = 0; j < HC_S; ++j)
                Z[i][j] = Hres[i * HC_S + j] * (1.0f / HC_TAU);

        for (int it = 0; it < HC_ITERS; ++it) {
            #pragma unroll
            for (int i = 0; i < HC_S; ++i)
                u[i] = -lse4_fast(Z[i][0] + v[0], Z[i][1] + v[1],
                                  Z[i][2] + v[2], Z[i][3] + v[3]);
            #pragma unroll
            for (int j = 0; j < HC_S; ++j)
                v[j] = -lse4_fast(Z[0][j] + u[0], Z[1][j] + u[1],
                                  Z[2][j] + u[2], Z[3][j] + u[3]);
        }

        float hp[HC_S];
        float m = fmaxf(fmaxf(Hpre[0], Hpre[1]), fmaxf(Hpre[2], Hpre[3]));
        float ssum = 0.f;
        #pragma unroll
        for (int s = 0; s < HC_S; ++s) { hp[s] = __expf(Hpre[s] - m); ssum += hp[s]; }
        float inv = 1.0f / ssum;
        #pragma unroll
        for (int s = 0; s < HC_S; ++s) hp[s] *= inv;

        float bt[HC_S];
        m = fmaxf(fmaxf(Hpost[0], Hpost[1]), fmaxf(Hpost[2], Hpost[3]));
        ssum = 0.f;
        #pragma unroll
        for (int t = 0; t < HC_S; ++t) { bt[t] = __expf(Hpost[t] - m); ssum += bt[t]; }
        inv = 1.0f / ssum;
        #pragma unroll
        for (int t = 0; t < HC_S; ++t) bt[t] *= inv;

        // M[t][s] = h_res[s][t] + beta[t]*h_pre[s]; h_res[s][t]=exp(Z[s][t]+u[s]+v[t])
        #pragma unroll
        for (int t = 0; t < HC_S; ++t)
            #pragma unroll
            for (int s = 0; s < HC_S; ++s)
                Ms[t * HC_S + s] = __expf(Z[s][t] + u[s] + v[t]) + bt[t] * hp[s];
    }
    __syncthreads();

    float M[16];
    #pragma unroll
    for (int k = 0; k < 16; ++k) M[k] = Ms[k];

    // ---- compute + store all 16 outputs ----
    #pragma unroll
    for (int b = 0; b < 4; ++b) {
        f4* po = out + (size_t)b * BATCH_STRIDE + r;
        #pragma unroll
        for (int t = 0; t < 4; ++t) {
            f4 o;
            o.x = M[4*t+0]*q[b][0].x + M[4*t+1]*q[b][1].x + M[4*t+2]*q[b][2].x + M[4*t+3]*q[b][3].x;
            o.y = M[4*t+0]*q[b][0].y + M[4*t+1]*q[b][1].y + M[4*t+2]*q[b][2].y + M[4*t+3]*q[b][3].y;
            o.z = M[4*t+0]*q[b][0].z + M[4*t+1]*q[b][1].z + M[4*t+2]*q[b][2].z + M[4*t+3]*q[b][3].z;
            o.w = M[4*t+0]*q[b][0].w + M[4*t+1]*q[b][1].w + M[4*t+2]*q[b][2].w + M[4*t+3]*q[b][3].w;
            po[(size_t)t * ND4] = o;
        }
    }
}

extern "C" void kernel_launch(void* const* d_in, const int* in_sizes, int n_in,
                              void* d_out, int out_size, void* d_ws, size_t ws_size,
                              hipStream_t stream) {
    const f4* in       = (const f4*)d_in[0];
    const float* Hres  = (const float*)d_in[1];
    const float* Hpre  = (const float*)d_in[2];
    const float* Hpost = (const float*)d_in[3];
    f4* out = (f4*)d_out;

    // ND4/256 = 2048 blocks; each thread handles one r across 4 batches.
    hc_mix_kernel<<<ND4 / 256, 256, 0, stream>>>(in, out, Hres, Hpre, Hpost);
}

// Round 8
// 48.587 us; speedup vs baseline: 1.1902x; 1.1902x over previous
//
#include <hip/hip_runtime.h>
#include <math.h>

// HyperConnections: out[(b*S+t), n, d] = sum_s M[t][s] * in[(b*S+s), n, d]
// M[t][s] = sinkhorn(H_res/tau)[s][t] + softmax(H_post)[t] * softmax(H_pre)[s]
//
// B=4, S=4, N=2048, D=1024, fp32. Memory-bound: 128 MiB in + 128 MiB out.
// Each thread owns TWO r positions (r0, r0+256) and processes all 4 batches.
// Thread-0 computes M (fast-math Sinkhorn) overlapped with the batch-0 loads
// issued before it; batch b+1 loads are prefetched in source order before
// batch b's stores (no asm pinning -- R7 showed forcing completion stalls).

#define HC_S 4
#define HC_TAU 0.05f
#define HC_ITERS 10

typedef float f4 __attribute__((ext_vector_type(4)));

// N*D/4 float4 elements per stream = 2048*1024/4 = 524288 = 2^19
constexpr int ND4 = (2048 * 1024) / 4;
constexpr size_t BATCH_STRIDE = (size_t)4 * ND4;   // 4 streams per batch
constexpr int RPT = 2;                              // r-positions per thread

__device__ inline float lse4_fast(float a, float b, float c, float d) {
    float m = fmaxf(fmaxf(a, b), fmaxf(c, d));
    return m + __logf(__expf(a - m) + __expf(b - m) + __expf(c - m) + __expf(d - m));
}

__global__ __launch_bounds__(256) void hc_mix_kernel(
    const f4* __restrict__ in, f4* __restrict__ out,
    const float* __restrict__ Hres, const float* __restrict__ Hpre,
    const float* __restrict__ Hpost)
{
    __shared__ float Ms[16];

    // Two r positions per thread: r, r+256 (both wave-coalesced).
    const size_t r = (size_t)blockIdx.x * (256 * RPT) + threadIdx.x;

    // ---- issue batch-0 loads first: 8 x 16B per lane in flight ----
    f4 q[RPT][4];
    #pragma unroll
    for (int j = 0; j < RPT; ++j) {
        const f4* pb = in + r + j * 256;
        #pragma unroll
        for (int s = 0; s < 4; ++s)
            q[j][s] = pb[(size_t)s * ND4];
    }

    if (threadIdx.x == 0) {
        // --- log-domain Sinkhorn on 4x4 (10 iters, tau=0.05), fast-math ---
        float Z[HC_S][HC_S], u[HC_S], v[HC_S];
        #pragma unroll
        for (int i = 0; i < HC_S; ++i) { u[i] = 0.f; v[i] = 0.f; }
        #pragma unroll
        for (int i = 0; i < HC_S; ++i)
            #pragma unroll
            for (int j = 0; j < HC_S; ++j)
                Z[i][j] = Hres[i * HC_S + j] * (1.0f / HC_TAU);

        for (int it = 0; it < HC_ITERS; ++it) {
            #pragma unroll
            for (int i = 0; i < HC_S; ++i)
                u[i] = -lse4_fast(Z[i][0] + v[0], Z[i][1] + v[1],
                                  Z[i][2] + v[2], Z[i][3] + v[3]);
            #pragma unroll
            for (int j = 0; j < HC_S; ++j)
                v[j] = -lse4_fast(Z[0][j] + u[0], Z[1][j] + u[1],
                                  Z[2][j] + u[2], Z[3][j] + u[3]);
        }

        float hp[HC_S];
        float m = fmaxf(fmaxf(Hpre[0], Hpre[1]), fmaxf(Hpre[2], Hpre[3]));
        float ssum = 0.f;
        #pragma unroll
        for (int s = 0; s < HC_S; ++s) { hp[s] = __expf(Hpre[s] - m); ssum += hp[s]; }
        float inv = 1.0f / ssum;
        #pragma unroll
        for (int s = 0; s < HC_S; ++s) hp[s] *= inv;

        float bt[HC_S];
        m = fmaxf(fmaxf(Hpost[0], Hpost[1]), fmaxf(Hpost[2], Hpost[3]));
        ssum = 0.f;
        #pragma unroll
        for (int t = 0; t < HC_S; ++t) { bt[t] = __expf(Hpost[t] - m); ssum += bt[t]; }
        inv = 1.0f / ssum;
        #pragma unroll
        for (int t = 0; t < HC_S; ++t) bt[t] *= inv;

        // M[t][s] = h_res[s][t] + beta[t]*h_pre[s]; h_res[s][t]=exp(Z[s][t]+u[s]+v[t])
        #pragma unroll
        for (int t = 0; t < HC_S; ++t)
            #pragma unroll
            for (int s = 0; s < HC_S; ++s)
                Ms[t * HC_S + s] = __expf(Z[s][t] + u[s] + v[t]) + bt[t] * hp[s];
    }
    __syncthreads();

    float M[16];
    #pragma unroll
    for (int k = 0; k < 16; ++k) M[k] = Ms[k];

    // ---- 4-batch pipeline: prefetch b+1 (source order), compute/store b ----
    #pragma unroll
    for (int b = 0; b < 4; ++b) {
        f4 nx[RPT][4];
        if (b < 3) {
            #pragma unroll
            for (int j = 0; j < RPT; ++j) {
                const f4* pn = in + (size_t)(b + 1) * BATCH_STRIDE + r + j * 256;
                #pragma unroll
                for (int s = 0; s < 4; ++s)
                    nx[j][s] = pn[(size_t)s * ND4];
            }
        }

        #pragma unroll
        for (int j = 0; j < RPT; ++j) {
            f4* po = out + (size_t)b * BATCH_STRIDE + r + j * 256;
            #pragma unroll
            for (int t = 0; t < 4; ++t) {
                f4 o;
                o.x = M[4*t+0]*q[j][0].x + M[4*t+1]*q[j][1].x + M[4*t+2]*q[j][2].x + M[4*t+3]*q[j][3].x;
                o.y = M[4*t+0]*q[j][0].y + M[4*t+1]*q[j][1].y + M[4*t+2]*q[j][2].y + M[4*t+3]*q[j][3].y;
                o.z = M[4*t+0]*q[j][0].z + M[4*t+1]*q[j][1].z + M[4*t+2]*q[j][2].z + M[4*t+3]*q[j][3].z;
                o.w = M[4*t+0]*q[j][0].w + M[4*t+1]*q[j][1].w + M[4*t+2]*q[j][2].w + M[4*t+3]*q[j][3].w;
                po[(size_t)t * ND4] = o;
            }
        }

        if (b < 3) {
            #pragma unroll
            for (int j = 0; j < RPT; ++j)
                #pragma unroll
                for (int s = 0; s < 4; ++s)
                    q[j][s] = nx[j][s];
        }
    }
}

extern "C" void kernel_launch(void* const* d_in, const int* in_sizes, int n_in,
                              void* d_out, int out_size, void* d_ws, size_t ws_size,
                              hipStream_t stream) {
    const f4* in       = (const f4*)d_in[0];
    const float* Hres  = (const float*)d_in[1];
    const float* Hpre  = (const float*)d_in[2];
    const float* Hpost = (const float*)d_in[3];
    f4* out = (f4*)d_out;

    // ND4/(256*RPT) = 1024 blocks; each thread: 2 r-positions x 4 batches.
    hc_mix_kernel<<<ND4 / (256 * RPT), 256, 0, stream>>>(in, out, Hres, Hpre, Hpost);
}